// Round 6
// baseline (26.436 us; speedup 1.0000x reference)
//
#include <hip/hip_runtime.h>

// Problem constants (match reference)
#define HH    128
#define WW    128
#define CDIM  4
#define DK    3
#define FDIM  4
#define DEPTH 16
#define DOUT  14
#define NB    4
#define HW    (HH * WW)          // 16384
#define TROWS 4                  // output rows per block
#define HROWS (TROWS + 2)        // halo rows of Q per block
#define NTILE (HH / TROWS)       // 32 h-tiles
#define IB    7                  // i-values per block (14 = 7 + 7)
#define NIG   2
#define NPL   (IB + DK - 1)      // 9 x-planes per (c)

typedef float nfloat4 __attribute__((ext_vector_type(4)));  // native vec for nt-store

// ---------------------------------------------------------------------------
// Kernel A: bsum[f,h,w] = sum_{c,dd} bias[f,0,c,dd,h,w]
// ---------------------------------------------------------------------------
__global__ __launch_bounds__(256) void bsum_kernel(const float* __restrict__ bias,
                                                   float* __restrict__ bsum) {
    int idx = blockIdx.x * 256 + threadIdx.x;     // over f*H*W = 65536
    int f  = idx >> 14;
    int hw = idx & 16383;
    const float* bp = bias + f * (CDIM * DK * HW) + hw;
    float s = 0.f;
#pragma unroll
    for (int c = 0; c < CDIM; ++c)
#pragma unroll
        for (int dd = 0; dd < DK; ++dd)
            s += bp[c * (DK * HW) + dd * HW];
    bsum[idx] = s;
}

// ---------------------------------------------------------------------------
// Kernel B: fused Q + 3x3 box-sum + leaky ReLU, 7 depth-outputs per block.
// Block: (b, i-half, 4-row h-tile) -> 256 blocks = 1 per CU.
// Weights loaded once per block, reused across 7 depth windows in registers.
// ---------------------------------------------------------------------------
__global__ __launch_bounds__(256, 1) void linerconv_main(const float* __restrict__ x,
                                                         const float* __restrict__ wgt,
                                                         const float* __restrict__ bsum,
                                                         float* __restrict__ out) {
    const int blk  = blockIdx.x;
    const int tile = blk & (NTILE - 1);
    const int ig   = (blk >> 5) & (NIG - 1);
    const int b    = blk >> 6;
    const int i0   = ig * IB;                 // 0 or 7
    const int h0   = tile * TROWS;

    __shared__ float lds[IB][FDIM][HROWS][WW]; // 7*4*6*128*4B = 84 KB

    const int tid = threadIdx.x;

    // ---- Phase 1: 192 threads fill HROWS x WW of Q for 7 i and 4 f ----
    if (tid < HROWS * 32) {
        const int row = tid >> 5;             // 0..5
        const int q   = tid & 31;
        const int g   = h0 - 1 + row;
        if (g >= 0 && g < HH) {
            const int base_hw = g * WW + q * 4;
            const float* xb = x + (b * CDIM * DEPTH + i0) * HW + base_hw;
            const float* wb = wgt + base_hw;
            float4 acc[IB][FDIM];
#pragma unroll
            for (int f = 0; f < FDIM; ++f) {
                float4 bv = *(const float4*)(bsum + f * HW + base_hw);
#pragma unroll
                for (int i2 = 0; i2 < IB; ++i2) acc[i2][f] = bv;
            }
#pragma unroll
            for (int c = 0; c < CDIM; ++c) {
                float4 xp[NPL];               // planes i0 .. i0+8
#pragma unroll
                for (int j = 0; j < NPL; ++j)
                    xp[j] = *(const float4*)(xb + c * (DEPTH * HW) + j * HW);
#pragma unroll
                for (int dd = 0; dd < DK; ++dd) {
#pragma unroll
                    for (int f = 0; f < FDIM; ++f) {
                        float4 wv = *(const float4*)(wb + ((f * CDIM + c) * DK + dd) * HW);
#pragma unroll
                        for (int i2 = 0; i2 < IB; ++i2) {
                            acc[i2][f].x += xp[i2 + dd].x * wv.x;
                            acc[i2][f].y += xp[i2 + dd].y * wv.y;
                            acc[i2][f].z += xp[i2 + dd].z * wv.z;
                            acc[i2][f].w += xp[i2 + dd].w * wv.w;
                        }
                    }
                }
            }
#pragma unroll
            for (int i2 = 0; i2 < IB; ++i2)
#pragma unroll
                for (int f = 0; f < FDIM; ++f)
                    *(float4*)&lds[i2][f][row][q * 4] = acc[i2][f];
        } else {
            float4 z = make_float4(0.f, 0.f, 0.f, 0.f);
#pragma unroll
            for (int i2 = 0; i2 < IB; ++i2)
#pragma unroll
                for (int f = 0; f < FDIM; ++f)
                    *(float4*)&lds[i2][f][row][q * 4] = z;
        }
    }
    __syncthreads();

    // ---- Phase 2: vectorized column box sums + leaky, float4 nt-stores ----
    // quad-columns: (i2, f, q) = 7*4*32 = 896 -> 3..4 per thread.
    for (int u = tid; u < IB * FDIM * 32; u += 256) {
        const int q  = u & 31;
        const int f  = (u >> 5) & 3;
        const int i2 = u >> 7;                // 0..6
        const float* Lb = &lds[i2][f][0][0];
        float4 rs[HROWS];
#pragma unroll
        for (int g = 0; g < HROWS; ++g) {
            const float* Lr = Lb + g * WW;
            float4 m  = *(const float4*)(Lr + q * 4);
            float lft = (q > 0)  ? Lr[q * 4 - 1] : 0.f;
            float rgt = (q < 31) ? Lr[q * 4 + 4] : 0.f;
            rs[g].x = lft + m.x + m.y;
            rs[g].y = m.x + m.y + m.z;
            rs[g].z = m.y + m.z + m.w;
            rs[g].w = m.z + m.w + rgt;
        }
        float* op = out + ((b * FDIM + f) * DOUT + (i0 + i2)) * HW + h0 * WW + q * 4;
#pragma unroll
        for (int r = 0; r < TROWS; ++r) {
            nfloat4 s;
            s.x = rs[r].x + rs[r + 1].x + rs[r + 2].x;
            s.y = rs[r].y + rs[r + 1].y + rs[r + 2].y;
            s.z = rs[r].z + rs[r + 1].z + rs[r + 2].z;
            s.w = rs[r].w + rs[r + 1].w + rs[r + 2].w;
            s.x = (s.x >= 0.f) ? s.x : 0.2f * s.x;
            s.y = (s.y >= 0.f) ? s.y : 0.2f * s.y;
            s.z = (s.z >= 0.f) ? s.z : 0.2f * s.z;
            s.w = (s.w >= 0.f) ? s.w : 0.2f * s.w;
            __builtin_nontemporal_store(s, (nfloat4*)(op + r * WW));
        }
    }
}

extern "C" void kernel_launch(void* const* d_in, const int* in_sizes, int n_in,
                              void* d_out, int out_size, void* d_ws, size_t ws_size,
                              hipStream_t stream) {
    const float* x    = (const float*)d_in[0];   // [4,4,16,128,128]
    const float* wgt  = (const float*)d_in[1];   // [4,1,4,3,128,128]
    const float* bias = (const float*)d_in[2];   // [4,1,4,3,128,128]
    float* out  = (float*)d_out;                 // [4,4,14,128,128]
    float* bsum = (float*)d_ws;                  // 65536 floats = 256 KB

    bsum_kernel<<<256, 256, 0, stream>>>(bias, bsum);
    linerconv_main<<<NB * NIG * NTILE, 256, 0, stream>>>(x, wgt, bsum, out);
}